// Round 12
// baseline (245.606 us; speedup 1.0000x reference)
//
#include <hip/hip_runtime.h>
#include <stdint.h>

// LeNet5-XNOR fused pipeline, round 12.
// vs round 11 (conv2lin / prepsum / reduce / mean byte-identical):
//  - conv1_mfma: tap->K-slot remap so every lane's 8 A-offsets are
//    COMPILE-TIME constants off one of two bases (khsel*64 for K-half 0,
//    khsel*4 for K-half 1; pad slots carry zero weights). This lets the
//    compiler fold ds imm offsets and merge pairs into ds_read2_b32:
//    ~16 DS instr + 16 v_adds -> ~8 DS instr + 2 v_adds per py.
//    LDS pad words 1024..1031 zeroed (pad slots may read them).

#define NIMG 8192

typedef __attribute__((ext_vector_type(8))) _Float16 f16x8;
typedef __attribute__((ext_vector_type(16))) float f32x16;

// ---------------- workspace layout ----------------
// 0       : 20 f32     mean
// 128     : 1250 u32   wp2
// 5632    : 500 f32    alpha
// 7680    : 500*20 u64 lwp
// 87808   : 256*1024 f32 partial image sums
// 1136384 : 8192*196 u32 b1p   (ends 7558912)
// 7558912 : 8*1024 f32 partial2

__global__ __launch_bounds__(256) void prepsum_k(const float* __restrict__ lw,
                                                 const float* __restrict__ w2,
                                                 const float* __restrict__ x,
                                                 unsigned long long* __restrict__ lwp,
                                                 float* __restrict__ alpha,
                                                 uint32_t* __restrict__ wp2,
                                                 float* __restrict__ partial) {
  int b = blockIdx.x, tid = threadIdx.x;
  if (b < 125) {
    int wave = tid >> 6, lane = tid & 63;
    int j = b * 4 + wave;
    float pa = 0.f;
    for (int k = lane; k < 1250; k += 64) pa += fabsf(lw[j * 1250 + k]);
    for (int o = 32; o > 0; o >>= 1) pa += __shfl_down(pa, o, 64);
    if (lane == 0) alpha[j] = pa / 1250.0f;
    if (lane < 20) {
      unsigned long long m = 0;
      int base = j * 1250 + lane * 64;
      int lim = 1250 - lane * 64; if (lim > 64) lim = 64;
      for (int bb = 0; bb < lim; ++bb)
        if (lw[base + bb] > 0.f) m |= (1ull << bb);
      lwp[j * 20 + lane] = m;
    }
  } else if (b < 130) {
    int idx = (b - 125) * 256 + tid;
    if (idx < 1250) {
      int oc = idx / 25, k = idx % 25;
      uint32_t m = 0;
      for (int ic = 0; ic < 20; ++ic)
        if (w2[(oc * 20 + ic) * 25 + k] > 0.f) m |= (1u << ic);
      wp2[idx] = m;
    }
  } else {
    int sb = b - 130;
    const float4* xv = (const float4*)x + (size_t)sb * 32 * 256;
    float ax = 0.f, ay = 0.f, az = 0.f, aw = 0.f;
    for (int nn = 0; nn < 32; ++nn) {
      float4 v = xv[nn * 256 + tid];
      ax += v.x; ay += v.y; az += v.z; aw += v.w;
    }
    float4 r; r.x = ax; r.y = ay; r.z = az; r.w = aw;
    ((float4*)(partial + (size_t)sb * 1024))[tid] = r;
  }
}

__global__ __launch_bounds__(256) void reduce_k(const float* __restrict__ partial,
                                                float* __restrict__ partial2) {
  int b = blockIdx.x, tid = threadIdx.x;
  int e = (b & 3) * 256 + tid;
  int p0 = (b >> 2) * 32;
  float s = 0.f;
#pragma unroll
  for (int p = 0; p < 32; ++p) s += partial[(size_t)(p0 + p) * 1024 + e];
  partial2[(size_t)(b >> 2) * 1024 + e] = s;
}

__global__ __launch_bounds__(256) void mean_k(const float* __restrict__ partial2,
                                              const float* __restrict__ w1,
                                              float* __restrict__ mean) {
  __shared__ float Tsh[1024];
  __shared__ double U8[25][8];
  __shared__ double U[25];
  int t = threadIdx.x;
  for (int e = t; e < 1024; e += 256) {
    double s = 0.0;
#pragma unroll
    for (int b = 0; b < 8; ++b) s += (double)partial2[b * 1024 + e];
    Tsh[e] = (float)s;
  }
  __syncthreads();
  if (t < 200) {
    int tap = t >> 3, part = t & 7;
    int ky = tap / 5, kx = tap % 5;
    double s = 0.0;
    for (int p = part * 98; p < part * 98 + 98; ++p) {
      int py = p / 28, px = p % 28;
      s += (double)Tsh[(py + ky) * 32 + px + kx];
    }
    U8[tap][part] = s;
  }
  __syncthreads();
  if (t < 25) {
    double s = 0.0;
    for (int i = 0; i < 8; ++i) s += U8[t][i];
    U[t] = s;
  }
  __syncthreads();
  if (t < 20) {
    double s = 0.0;
    for (int q = 0; q < 25; ++q) s += (double)w1[t * 25 + q] * U[q];
    mean[t] = (float)(s / (8192.0 * 784.0));
  }
}

__device__ inline uint32_t pack_f16_pair(float fv) {
  _Float16 h = (_Float16)fv;
  float rem = fv - (float)h;
  _Float16 l = (_Float16)(rem * 4096.0f);
  uint32_t hb = (uint32_t)__builtin_bit_cast(unsigned short, h);
  uint32_t lb = (uint32_t)__builtin_bit_cast(unsigned short, l);
  return (hb << 16) | lb;
}

// conv1 via MFMA (fp16 2-limb split). One wave per image; block = 4 images.
// K-slot mapping (slot j of K-half kh, lane group khsel):
//   kh=0: tap = j + khsel*10            (offsets {0,1,2,3,4,32,33,34} + khsel*64)
//   kh=1, khsel=0: taps {8,9,18,19,20,21,22,23}  (offsets {35,36,99,100,128..131})
//   kh=1, khsel=1: offsets +4; only slot 4 (elem 132 = tap 24) has nonzero weight.
__global__ __launch_bounds__(256) void conv1_mfma_k(const float* __restrict__ x,
                                                    const float* __restrict__ w1,
                                                    const float* __restrict__ mean,
                                                    uint32_t* __restrict__ b1p) {
  __shared__ uint32_t ximg[4][1032];
  int tid = threadIdx.x;
  int wave = tid >> 6, lane = tid & 63;
  int n = blockIdx.x * 4 + wave;
  uint32_t* xs = ximg[wave];

  const float4* xin = (const float4*)(x + (size_t)n * 1024);
#pragma unroll
  for (int i = 0; i < 4; ++i) {
    float4 v = xin[i * 64 + lane];
    float fv[4] = {v.x, v.y, v.z, v.w};
#pragma unroll
    for (int e = 0; e < 4; ++e)
      xs[4 * (i * 64 + lane) + e] = pack_f16_pair(fv[e]);
  }
  if (lane < 8) xs[1024 + lane] = 0;  // pad slots may read here

  int bc = lane & 31;
  int khsel = lane >> 5;
  f16x8 Bh[2], Bl[2];
  const int t1tab[8] = {8, 9, 18, 19, 20, 21, 22, 23};
#pragma unroll
  for (int j = 0; j < 8; ++j) {
    // K-half 0
    int t0 = j + khsel * 10;
    float wv0 = (bc < 20) ? w1[bc * 25 + t0] : 0.f;
    uint32_t p0 = pack_f16_pair(wv0);
    Bh[0][j] = __builtin_bit_cast(_Float16, (unsigned short)(p0 >> 16));
    Bl[0][j] = __builtin_bit_cast(_Float16, (unsigned short)(p0 & 0xffffu));
    // K-half 1
    float wv1 = 0.f;
    if (bc < 20) {
      if (khsel == 0) wv1 = w1[bc * 25 + t1tab[j]];
      else if (j == 4) wv1 = w1[bc * 25 + 24];
    }
    uint32_t p1 = pack_f16_pair(wv1);
    Bh[1][j] = __builtin_bit_cast(_Float16, (unsigned short)(p1 >> 16));
    Bl[1][j] = __builtin_bit_cast(_Float16, (unsigned short)(p1 & 0xffffu));
  }
  float mv = (bc < 20) ? mean[bc] : 3.0e38f;

  int m = lane & 31;
  int d0 = m + khsel * 64;  // K-half-0 base offset (from row start)
  int d1 = m + khsel * 4;   // K-half-1 base offset
  const float INV = 1.0f / 4096.0f;

  for (int pp = 0; pp < 14; ++pp) {
    unsigned long long bacc[16];
#pragma unroll
    for (int r = 0; r < 16; ++r) bacc[r] = 0ull;
#pragma unroll
    for (int py2 = 0; py2 < 2; ++py2) {
      int pybase = (2 * pp + py2) * 32;
      const uint32_t* b0 = xs + pybase + d0;
      const uint32_t* b1 = xs + pybase + d1;
      uint32_t raw[16];
      raw[0] = b0[0];   raw[1] = b0[1];   raw[2] = b0[2];   raw[3] = b0[3];
      raw[4] = b0[4];   raw[5] = b0[32];  raw[6] = b0[33];  raw[7] = b0[34];
      raw[8] = b1[35];  raw[9] = b1[36];  raw[10] = b1[99]; raw[11] = b1[100];
      raw[12] = b1[128]; raw[13] = b1[129]; raw[14] = b1[130]; raw[15] = b1[131];
      f16x8 Ah[2], Al[2];
#pragma unroll
      for (int kh = 0; kh < 2; ++kh) {
        uint32_t hw[4], lw2[4];
#pragma unroll
        for (int jj = 0; jj < 4; ++jj) {
          uint32_t v0 = raw[kh * 8 + 2 * jj], v1 = raw[kh * 8 + 2 * jj + 1];
          hw[jj] = (v1 & 0xFFFF0000u) | (v0 >> 16);
          lw2[jj] = (v1 << 16) | (v0 & 0xFFFFu);
        }
        struct U4 { uint32_t a, b, c, d; };
        U4 hv4 = {hw[0], hw[1], hw[2], hw[3]};
        U4 lv4 = {lw2[0], lw2[1], lw2[2], lw2[3]};
        Ah[kh] = __builtin_bit_cast(f16x8, hv4);
        Al[kh] = __builtin_bit_cast(f16x8, lv4);
      }
      f32x16 acc0, acc1;
#pragma unroll
      for (int i = 0; i < 16; ++i) { acc0[i] = 0.f; acc1[i] = 0.f; }
      acc0 = __builtin_amdgcn_mfma_f32_32x32x16_f16(Ah[0], Bh[0], acc0, 0, 0, 0);
      acc0 = __builtin_amdgcn_mfma_f32_32x32x16_f16(Ah[1], Bh[1], acc0, 0, 0, 0);
      acc1 = __builtin_amdgcn_mfma_f32_32x32x16_f16(Ah[0], Bl[0], acc1, 0, 0, 0);
      acc1 = __builtin_amdgcn_mfma_f32_32x32x16_f16(Ah[1], Bl[1], acc1, 0, 0, 0);
      acc1 = __builtin_amdgcn_mfma_f32_32x32x16_f16(Al[0], Bh[0], acc1, 0, 0, 0);
      acc1 = __builtin_amdgcn_mfma_f32_32x32x16_f16(Al[1], Bh[1], acc1, 0, 0, 0);
#pragma unroll
      for (int r = 0; r < 16; ++r)
        bacc[r] |= __ballot((acc0[r] + INV * acc1[r]) > mv);
    }
    uint32_t pm = 0;
#pragma unroll
    for (int pc = 0; pc < 14; ++pc) {
      int px0 = 2 * pc;
      int r0 = (px0 & 3) + 4 * (px0 >> 3);
      int h0 = (px0 >> 2) & 1;
      unsigned long long mm = bacc[r0] | bacc[r0 + 1];
      uint32_t val = (uint32_t)(mm >> (32 * h0));
      if (lane == pc) pm = val;
    }
    if (lane < 14) b1p[(size_t)n * 196 + pp * 14 + lane] = pm;
  }
}

// Fused conv2+pool/sign+linear+fc. Round-10/11 version verbatim.
__global__ __launch_bounds__(512) void conv2lin_k(const uint32_t* __restrict__ b1p,
                                                  const uint32_t* __restrict__ wp2,
                                                  const unsigned long long* __restrict__ lwp,
                                                  const float* __restrict__ alpha,
                                                  const float* __restrict__ fcw,
                                                  const float* __restrict__ fcb,
                                                  float* __restrict__ out) {
  __shared__ uint32_t wsh[1250];
  __shared__ uint32_t bm[8][196];
  __shared__ int sumpc[8][100];
  __shared__ char uni[8][2048];
  int tid = threadIdx.x;
  int wave = tid >> 6, lane = tid & 63;
  int n = blockIdx.x * 8 + wave;
  signed char* s2w = (signed char*)uni[wave];
  float* hshw = (float*)uni[wave];

  for (int i = tid; i < 1250; i += 512) wsh[i] = wp2[i];
#pragma unroll
  for (int rd = 0; rd < 4; ++rd) {
    int idx = rd * 64 + lane;
    if (idx < 196) bm[wave][idx] = b1p[(size_t)n * 196 + idx];
  }
  __syncthreads();

#pragma unroll
  for (int rd = 0; rd < 2; ++rd) {
    int pp = rd * 64 + lane;
    if (pp < 100) {
      int Y = pp / 10, X = pp % 10, s = 0;
#pragma unroll
      for (int ky = 0; ky < 5; ++ky)
#pragma unroll
        for (int kx = 0; kx < 5; ++kx)
          s += __popc(bm[wave][(Y + ky) * 14 + X + kx]);
      sumpc[wave][pp] = s;
    }
  }

#pragma unroll
  for (int rd = 0; rd < 4; ++rd) {
    int unit = rd * 64 + lane;
    if (unit < 250) {
      int oc = unit / 5, r = unit % 5;
      uint32_t w[25];
#pragma unroll
      for (int i = 0; i < 25; ++i) w[i] = wsh[oc * 25 + i];
      for (int pc = 0; pc < 5; ++pc) {
        uint32_t pa[6][6];
#pragma unroll
        for (int rr = 0; rr < 6; ++rr)
#pragma unroll
          for (int cc = 0; cc < 6; ++cc)
            pa[rr][cc] = bm[wave][(2 * r + rr) * 14 + 2 * pc + cc];
        int best = -1000000;
#pragma unroll
        for (int dy = 0; dy < 2; ++dy)
#pragma unroll
          for (int dx = 0; dx < 2; ++dx) {
            int a = 0;
#pragma unroll
            for (int ky = 0; ky < 5; ++ky)
#pragma unroll
              for (int kx = 0; kx < 5; ++kx)
                a += __popc(w[ky * 5 + kx] & pa[dy + ky][dx + kx]);
            a = 2 * a - sumpc[wave][(2 * r + dy) * 10 + 2 * pc + dx];
            if (a > best) best = a;
          }
        s2w[5 * unit + pc] = (signed char)((best > 0) - (best < 0));
      }
    }
  }
  if (lane < 30) s2w[1250 + lane] = 0;

  unsigned long long Pm[20], Nm[20];
  int cp = 0, cn = 0;
#pragma unroll
  for (int k = 0; k < 20; ++k) {
    signed char v = s2w[k * 64 + lane];
    unsigned long long P = __ballot(v > 0);
    unsigned long long N = __ballot(v < 0);
    Pm[k] = P; Nm[k] = N;
    cp += __popcll(P); cn += __popcll(N);
  }

#pragma unroll
  for (int rd = 0; rd < 8; ++rd) {
    int j = rd * 64 + lane;
    float y = 0.f;
    if (j < 500) {
      const ulonglong2* W2 = (const ulonglong2*)(lwp + (size_t)j * 20);
      int a = 0, b = 0;
#pragma unroll
      for (int i = 0; i < 10; ++i) {
        ulonglong2 w2v = W2[i];
        a += __popcll(w2v.x & Pm[2 * i]) + __popcll(w2v.y & Pm[2 * i + 1]);
        b += __popcll(w2v.x & Nm[2 * i]) + __popcll(w2v.y & Nm[2 * i + 1]);
      }
      int dot = 2 * (a - b) - cp + cn;
      y = alpha[j] * (float)dot;
      y = fminf(1.0f, fmaxf(-1.0f, y));
    }
    hshw[rd * 64 + lane] = y;
  }

  float hv[8];
#pragma unroll
  for (int k = 0; k < 8; ++k) hv[k] = hshw[k * 64 + lane];
#pragma unroll
  for (int o = 0; o < 10; ++o) {
    float pa = 0.f;
#pragma unroll
    for (int k = 0; k < 8; ++k) {
      int j = k * 64 + lane;
      if (j < 500) pa += hv[k] * fcw[o * 500 + j];
    }
    for (int off = 32; off > 0; off >>= 1) pa += __shfl_down(pa, off, 64);
    if (lane == 0) out[(size_t)n * 10 + o] = pa + fcb[o];
  }
}

extern "C" void kernel_launch(void* const* d_in, const int* in_sizes, int n_in,
                              void* d_out, int out_size, void* d_ws, size_t ws_size,
                              hipStream_t stream) {
  const float* x   = (const float*)d_in[0];
  const float* w1  = (const float*)d_in[1];
  const float* w2  = (const float*)d_in[2];
  const float* lw  = (const float*)d_in[3];
  const float* fcw = (const float*)d_in[4];
  const float* fcb = (const float*)d_in[5];
  float* out = (float*)d_out;
  char* ws = (char*)d_ws;

  float*    mean  = (float*)(ws + 0);
  uint32_t* wp2   = (uint32_t*)(ws + 128);
  float*    alpha = (float*)(ws + 5632);
  unsigned long long* lwp = (unsigned long long*)(ws + 7680);
  float*    partial = (float*)(ws + 87808);
  uint32_t* b1p   = (uint32_t*)(ws + 1136384);
  float*    partial2 = (float*)(ws + 7558912);

  prepsum_k<<<386, 256, 0, stream>>>(lw, w2, x, lwp, alpha, wp2, partial);
  reduce_k<<<32, 256, 0, stream>>>(partial, partial2);
  mean_k<<<1, 256, 0, stream>>>(partial2, w1, mean);
  conv1_mfma_k<<<2048, 256, 0, stream>>>(x, w1, mean, b1p);
  conv2lin_k<<<1024, 512, 0, stream>>>(b1p, wp2, lwp, alpha, fcw, fcb, out);
}

// Round 13
// 241.547 us; speedup vs baseline: 1.0168x; 1.0168x over previous
//
#include <hip/hip_runtime.h>
#include <stdint.h>

// LeNet5-XNOR fused pipeline, round 13.
// vs round 12 (conv2lin byte-identical; mean path re-laid):
//  - conv1_mfma: __launch_bounds__(256,6) pins >=6 waves/SIMD (VGPR<=85) —
//    r11/r12 neutrality showed conv1 is latency-bound at fixed occupancy,
//    so occupancy is the lever. Limb unpack via explicit v_perm_b32
//    (1 op per merge instead of ~4, also lowers transient pressure).
//  - sumT: 512 blocks x 16 images (2 blocks/CU for the 32MB x read).

#define NIMG 8192

typedef __attribute__((ext_vector_type(8))) _Float16 f16x8;
typedef __attribute__((ext_vector_type(16))) float f32x16;

// ---------------- workspace layout ----------------
// 0       : 20 f32     mean
// 128     : 1250 u32   wp2
// 5632    : 500 f32    alpha
// 7680    : 500*20 u64 lwp
// 87808   : 512*1024 f32 partial image sums (ends 2184960)
// 2184960 : 8192*196 u32 b1p (ends 8607488)
// 8607488 : 16*1024 f32 partial2

// blocks 0..124: prep_lin; 125..129: wp2 pack; 130..641: sumT partials
__global__ __launch_bounds__(256) void prepsum_k(const float* __restrict__ lw,
                                                 const float* __restrict__ w2,
                                                 const float* __restrict__ x,
                                                 unsigned long long* __restrict__ lwp,
                                                 float* __restrict__ alpha,
                                                 uint32_t* __restrict__ wp2,
                                                 float* __restrict__ partial) {
  int b = blockIdx.x, tid = threadIdx.x;
  if (b < 125) {
    int wave = tid >> 6, lane = tid & 63;
    int j = b * 4 + wave;
    float pa = 0.f;
    for (int k = lane; k < 1250; k += 64) pa += fabsf(lw[j * 1250 + k]);
    for (int o = 32; o > 0; o >>= 1) pa += __shfl_down(pa, o, 64);
    if (lane == 0) alpha[j] = pa / 1250.0f;
    if (lane < 20) {
      unsigned long long m = 0;
      int base = j * 1250 + lane * 64;
      int lim = 1250 - lane * 64; if (lim > 64) lim = 64;
      for (int bb = 0; bb < lim; ++bb)
        if (lw[base + bb] > 0.f) m |= (1ull << bb);
      lwp[j * 20 + lane] = m;
    }
  } else if (b < 130) {
    int idx = (b - 125) * 256 + tid;
    if (idx < 1250) {
      int oc = idx / 25, k = idx % 25;
      uint32_t m = 0;
      for (int ic = 0; ic < 20; ++ic)
        if (w2[(oc * 20 + ic) * 25 + k] > 0.f) m |= (1u << ic);
      wp2[idx] = m;
    }
  } else {
    int sb = b - 130;
    const float4* xv = (const float4*)x + (size_t)sb * 16 * 256;
    float ax = 0.f, ay = 0.f, az = 0.f, aw = 0.f;
    for (int nn = 0; nn < 16; ++nn) {
      float4 v = xv[nn * 256 + tid];
      ax += v.x; ay += v.y; az += v.z; aw += v.w;
    }
    float4 r; r.x = ax; r.y = ay; r.z = az; r.w = aw;
    ((float4*)(partial + (size_t)sb * 1024))[tid] = r;
  }
}

// 512 partials -> 16. block b (0..63): elems (b&3)*256+tid, partial group b>>2.
__global__ __launch_bounds__(256) void reduce_k(const float* __restrict__ partial,
                                                float* __restrict__ partial2) {
  int b = blockIdx.x, tid = threadIdx.x;
  int e = (b & 3) * 256 + tid;
  int p0 = (b >> 2) * 32;
  float s = 0.f;
#pragma unroll
  for (int p = 0; p < 32; ++p) s += partial[(size_t)(p0 + p) * 1024 + e];
  partial2[(size_t)(b >> 2) * 1024 + e] = s;
}

__global__ __launch_bounds__(256) void mean_k(const float* __restrict__ partial2,
                                              const float* __restrict__ w1,
                                              float* __restrict__ mean) {
  __shared__ float Tsh[1024];
  __shared__ double U8[25][8];
  __shared__ double U[25];
  int t = threadIdx.x;
  for (int e = t; e < 1024; e += 256) {
    double s = 0.0;
#pragma unroll
    for (int b = 0; b < 16; ++b) s += (double)partial2[b * 1024 + e];
    Tsh[e] = (float)s;
  }
  __syncthreads();
  if (t < 200) {
    int tap = t >> 3, part = t & 7;
    int ky = tap / 5, kx = tap % 5;
    double s = 0.0;
    for (int p = part * 98; p < part * 98 + 98; ++p) {
      int py = p / 28, px = p % 28;
      s += (double)Tsh[(py + ky) * 32 + px + kx];
    }
    U8[tap][part] = s;
  }
  __syncthreads();
  if (t < 25) {
    double s = 0.0;
    for (int i = 0; i < 8; ++i) s += U8[t][i];
    U[t] = s;
  }
  __syncthreads();
  if (t < 20) {
    double s = 0.0;
    for (int q = 0; q < 25; ++q) s += (double)w1[t * 25 + q] * U[q];
    mean[t] = (float)(s / (8192.0 * 784.0));
  }
}

__device__ inline uint32_t pack_f16_pair(float fv) {
  _Float16 h = (_Float16)fv;
  float rem = fv - (float)h;
  _Float16 l = (_Float16)(rem * 4096.0f);
  uint32_t hb = (uint32_t)__builtin_bit_cast(unsigned short, h);
  uint32_t lb = (uint32_t)__builtin_bit_cast(unsigned short, l);
  return (hb << 16) | lb;
}

// conv1 via MFMA (fp16 2-limb split). One wave per image; block = 4 images.
// __launch_bounds__(256,6): pin 6 waves/SIMD (VGPR<=85).
__global__ __launch_bounds__(256, 6) void conv1_mfma_k(const float* __restrict__ x,
                                                       const float* __restrict__ w1,
                                                       const float* __restrict__ mean,
                                                       uint32_t* __restrict__ b1p) {
  __shared__ uint32_t ximg[4][1032];
  int tid = threadIdx.x;
  int wave = tid >> 6, lane = tid & 63;
  int n = blockIdx.x * 4 + wave;
  uint32_t* xs = ximg[wave];

  const float4* xin = (const float4*)(x + (size_t)n * 1024);
#pragma unroll
  for (int i = 0; i < 4; ++i) {
    float4 v = xin[i * 64 + lane];
    float fv[4] = {v.x, v.y, v.z, v.w};
#pragma unroll
    for (int e = 0; e < 4; ++e)
      xs[4 * (i * 64 + lane) + e] = pack_f16_pair(fv[e]);
  }
  if (lane < 8) xs[1024 + lane] = 0;  // pad slots may read here

  int bc = lane & 31;
  int khsel = lane >> 5;
  f16x8 Bh[2], Bl[2];
  const int t1tab[8] = {8, 9, 18, 19, 20, 21, 22, 23};
#pragma unroll
  for (int j = 0; j < 8; ++j) {
    int t0 = j + khsel * 10;
    float wv0 = (bc < 20) ? w1[bc * 25 + t0] : 0.f;
    uint32_t p0 = pack_f16_pair(wv0);
    Bh[0][j] = __builtin_bit_cast(_Float16, (unsigned short)(p0 >> 16));
    Bl[0][j] = __builtin_bit_cast(_Float16, (unsigned short)(p0 & 0xffffu));
    float wv1 = 0.f;
    if (bc < 20) {
      if (khsel == 0) wv1 = w1[bc * 25 + t1tab[j]];
      else if (j == 4) wv1 = w1[bc * 25 + 24];
    }
    uint32_t p1 = pack_f16_pair(wv1);
    Bh[1][j] = __builtin_bit_cast(_Float16, (unsigned short)(p1 >> 16));
    Bl[1][j] = __builtin_bit_cast(_Float16, (unsigned short)(p1 & 0xffffu));
  }
  float mv = (bc < 20) ? mean[bc] : 3.0e38f;

  int m = lane & 31;
  int d0 = m + khsel * 64;
  int d1 = m + khsel * 4;
  const float INV = 1.0f / 4096.0f;

  for (int pp = 0; pp < 14; ++pp) {
    unsigned long long bacc[16];
#pragma unroll
    for (int r = 0; r < 16; ++r) bacc[r] = 0ull;
#pragma unroll
    for (int py2 = 0; py2 < 2; ++py2) {
      int pybase = (2 * pp + py2) * 32;
      const uint32_t* b0 = xs + pybase + d0;
      const uint32_t* b1 = xs + pybase + d1;
      uint32_t raw[16];
      raw[0] = b0[0];   raw[1] = b0[1];   raw[2] = b0[2];   raw[3] = b0[3];
      raw[4] = b0[4];   raw[5] = b0[32];  raw[6] = b0[33];  raw[7] = b0[34];
      raw[8] = b1[35];  raw[9] = b1[36];  raw[10] = b1[99]; raw[11] = b1[100];
      raw[12] = b1[128]; raw[13] = b1[129]; raw[14] = b1[130]; raw[15] = b1[131];
      f16x8 Ah[2], Al[2];
#pragma unroll
      for (int kh = 0; kh < 2; ++kh) {
        uint32_t hw[4], lw2[4];
#pragma unroll
        for (int jj = 0; jj < 4; ++jj) {
          uint32_t v0 = raw[kh * 8 + 2 * jj], v1 = raw[kh * 8 + 2 * jj + 1];
          // hw = (v1 & 0xFFFF0000) | (v0 >> 16) ; lw2 = (v1 << 16) | (v0 & 0xFFFF)
          hw[jj] = __builtin_amdgcn_perm(v1, v0, 0x07060302u);
          lw2[jj] = __builtin_amdgcn_perm(v1, v0, 0x05040100u);
        }
        struct U4 { uint32_t a, b, c, d; };
        U4 hv4 = {hw[0], hw[1], hw[2], hw[3]};
        U4 lv4 = {lw2[0], lw2[1], lw2[2], lw2[3]};
        Ah[kh] = __builtin_bit_cast(f16x8, hv4);
        Al[kh] = __builtin_bit_cast(f16x8, lv4);
      }
      f32x16 acc0, acc1;
#pragma unroll
      for (int i = 0; i < 16; ++i) { acc0[i] = 0.f; acc1[i] = 0.f; }
      acc0 = __builtin_amdgcn_mfma_f32_32x32x16_f16(Ah[0], Bh[0], acc0, 0, 0, 0);
      acc0 = __builtin_amdgcn_mfma_f32_32x32x16_f16(Ah[1], Bh[1], acc0, 0, 0, 0);
      acc1 = __builtin_amdgcn_mfma_f32_32x32x16_f16(Ah[0], Bl[0], acc1, 0, 0, 0);
      acc1 = __builtin_amdgcn_mfma_f32_32x32x16_f16(Ah[1], Bl[1], acc1, 0, 0, 0);
      acc1 = __builtin_amdgcn_mfma_f32_32x32x16_f16(Al[0], Bh[0], acc1, 0, 0, 0);
      acc1 = __builtin_amdgcn_mfma_f32_32x32x16_f16(Al[1], Bh[1], acc1, 0, 0, 0);
#pragma unroll
      for (int r = 0; r < 16; ++r)
        bacc[r] |= __ballot((acc0[r] + INV * acc1[r]) > mv);
    }
    uint32_t pm = 0;
#pragma unroll
    for (int pc = 0; pc < 14; ++pc) {
      int px0 = 2 * pc;
      int r0 = (px0 & 3) + 4 * (px0 >> 3);
      int h0 = (px0 >> 2) & 1;
      unsigned long long mm = bacc[r0] | bacc[r0 + 1];
      uint32_t val = (uint32_t)(mm >> (32 * h0));
      if (lane == pc) pm = val;
    }
    if (lane < 14) b1p[(size_t)n * 196 + pp * 14 + lane] = pm;
  }
}

// Fused conv2+pool/sign+linear+fc. Round-10/11/12 version verbatim.
__global__ __launch_bounds__(512) void conv2lin_k(const uint32_t* __restrict__ b1p,
                                                  const uint32_t* __restrict__ wp2,
                                                  const unsigned long long* __restrict__ lwp,
                                                  const float* __restrict__ alpha,
                                                  const float* __restrict__ fcw,
                                                  const float* __restrict__ fcb,
                                                  float* __restrict__ out) {
  __shared__ uint32_t wsh[1250];
  __shared__ uint32_t bm[8][196];
  __shared__ int sumpc[8][100];
  __shared__ char uni[8][2048];
  int tid = threadIdx.x;
  int wave = tid >> 6, lane = tid & 63;
  int n = blockIdx.x * 8 + wave;
  signed char* s2w = (signed char*)uni[wave];
  float* hshw = (float*)uni[wave];

  for (int i = tid; i < 1250; i += 512) wsh[i] = wp2[i];
#pragma unroll
  for (int rd = 0; rd < 4; ++rd) {
    int idx = rd * 64 + lane;
    if (idx < 196) bm[wave][idx] = b1p[(size_t)n * 196 + idx];
  }
  __syncthreads();

#pragma unroll
  for (int rd = 0; rd < 2; ++rd) {
    int pp = rd * 64 + lane;
    if (pp < 100) {
      int Y = pp / 10, X = pp % 10, s = 0;
#pragma unroll
      for (int ky = 0; ky < 5; ++ky)
#pragma unroll
        for (int kx = 0; kx < 5; ++kx)
          s += __popc(bm[wave][(Y + ky) * 14 + X + kx]);
      sumpc[wave][pp] = s;
    }
  }

#pragma unroll
  for (int rd = 0; rd < 4; ++rd) {
    int unit = rd * 64 + lane;
    if (unit < 250) {
      int oc = unit / 5, r = unit % 5;
      uint32_t w[25];
#pragma unroll
      for (int i = 0; i < 25; ++i) w[i] = wsh[oc * 25 + i];
      for (int pc = 0; pc < 5; ++pc) {
        uint32_t pa[6][6];
#pragma unroll
        for (int rr = 0; rr < 6; ++rr)
#pragma unroll
          for (int cc = 0; cc < 6; ++cc)
            pa[rr][cc] = bm[wave][(2 * r + rr) * 14 + 2 * pc + cc];
        int best = -1000000;
#pragma unroll
        for (int dy = 0; dy < 2; ++dy)
#pragma unroll
          for (int dx = 0; dx < 2; ++dx) {
            int a = 0;
#pragma unroll
            for (int ky = 0; ky < 5; ++ky)
#pragma unroll
              for (int kx = 0; kx < 5; ++kx)
                a += __popc(w[ky * 5 + kx] & pa[dy + ky][dx + kx]);
            a = 2 * a - sumpc[wave][(2 * r + dy) * 10 + 2 * pc + dx];
            if (a > best) best = a;
          }
        s2w[5 * unit + pc] = (signed char)((best > 0) - (best < 0));
      }
    }
  }
  if (lane < 30) s2w[1250 + lane] = 0;

  unsigned long long Pm[20], Nm[20];
  int cp = 0, cn = 0;
#pragma unroll
  for (int k = 0; k < 20; ++k) {
    signed char v = s2w[k * 64 + lane];
    unsigned long long P = __ballot(v > 0);
    unsigned long long N = __ballot(v < 0);
    Pm[k] = P; Nm[k] = N;
    cp += __popcll(P); cn += __popcll(N);
  }

#pragma unroll
  for (int rd = 0; rd < 8; ++rd) {
    int j = rd * 64 + lane;
    float y = 0.f;
    if (j < 500) {
      const ulonglong2* W2 = (const ulonglong2*)(lwp + (size_t)j * 20);
      int a = 0, b = 0;
#pragma unroll
      for (int i = 0; i < 10; ++i) {
        ulonglong2 w2v = W2[i];
        a += __popcll(w2v.x & Pm[2 * i]) + __popcll(w2v.y & Pm[2 * i + 1]);
        b += __popcll(w2v.x & Nm[2 * i]) + __popcll(w2v.y & Nm[2 * i + 1]);
      }
      int dot = 2 * (a - b) - cp + cn;
      y = alpha[j] * (float)dot;
      y = fminf(1.0f, fmaxf(-1.0f, y));
    }
    hshw[rd * 64 + lane] = y;
  }

  float hv[8];
#pragma unroll
  for (int k = 0; k < 8; ++k) hv[k] = hshw[k * 64 + lane];
#pragma unroll
  for (int o = 0; o < 10; ++o) {
    float pa = 0.f;
#pragma unroll
    for (int k = 0; k < 8; ++k) {
      int j = k * 64 + lane;
      if (j < 500) pa += hv[k] * fcw[o * 500 + j];
    }
    for (int off = 32; off > 0; off >>= 1) pa += __shfl_down(pa, off, 64);
    if (lane == 0) out[(size_t)n * 10 + o] = pa + fcb[o];
  }
}

extern "C" void kernel_launch(void* const* d_in, const int* in_sizes, int n_in,
                              void* d_out, int out_size, void* d_ws, size_t ws_size,
                              hipStream_t stream) {
  const float* x   = (const float*)d_in[0];
  const float* w1  = (const float*)d_in[1];
  const float* w2  = (const float*)d_in[2];
  const float* lw  = (const float*)d_in[3];
  const float* fcw = (const float*)d_in[4];
  const float* fcb = (const float*)d_in[5];
  float* out = (float*)d_out;
  char* ws = (char*)d_ws;

  float*    mean  = (float*)(ws + 0);
  uint32_t* wp2   = (uint32_t*)(ws + 128);
  float*    alpha = (float*)(ws + 5632);
  unsigned long long* lwp = (unsigned long long*)(ws + 7680);
  float*    partial = (float*)(ws + 87808);
  uint32_t* b1p   = (uint32_t*)(ws + 2184960);
  float*    partial2 = (float*)(ws + 8607488);

  prepsum_k<<<642, 256, 0, stream>>>(lw, w2, x, lwp, alpha, wp2, partial);
  reduce_k<<<64, 256, 0, stream>>>(partial, partial2);
  mean_k<<<1, 256, 0, stream>>>(partial2, w1, mean);
  conv1_mfma_k<<<2048, 256, 0, stream>>>(x, w1, mean, b1p);
  conv2lin_k<<<1024, 512, 0, stream>>>(b1p, wp2, lwp, alpha, fcw, fcb, out);
}

// Round 14
// 234.868 us; speedup vs baseline: 1.0457x; 1.0284x over previous
//
#include <hip/hip_runtime.h>
#include <stdint.h>

// LeNet5-XNOR fused pipeline, round 14.
// vs round 13 (conv2lin / prepsum / reduce / mean byte-identical):
//  - conv1_mfma: 2 waves per image (each wave does 7 of 14 row-pairs) —
//    halves the per-wave serial dependency chain that 3 rounds of
//    instruction-shaving couldn't touch. ximg shared via one barrier.
//  - conv1_mfma: single 4096-scaled accumulator chain: Bhs=w_hi*4096 (exact),
//    Bl=w_lo*4096, Al=x_lo*4096; acc = Ah*Bhs + Ah*Bl + Al*Bh accumulates
//    4096*(hh+hl+lh); threshold mean*4096. Deletes 16 fmaf/row + 16 VGPRs.

#define NIMG 8192

typedef __attribute__((ext_vector_type(8))) _Float16 f16x8;
typedef __attribute__((ext_vector_type(16))) float f32x16;

// ---------------- workspace layout ----------------
// 0       : 20 f32     mean
// 128     : 1250 u32   wp2
// 5632    : 500 f32    alpha
// 7680    : 500*20 u64 lwp
// 87808   : 512*1024 f32 partial (ends 2184960)
// 2184960 : 8192*196 u32 b1p (ends 8607488)
// 8607488 : 16*1024 f32 partial2

__global__ __launch_bounds__(256) void prepsum_k(const float* __restrict__ lw,
                                                 const float* __restrict__ w2,
                                                 const float* __restrict__ x,
                                                 unsigned long long* __restrict__ lwp,
                                                 float* __restrict__ alpha,
                                                 uint32_t* __restrict__ wp2,
                                                 float* __restrict__ partial) {
  int b = blockIdx.x, tid = threadIdx.x;
  if (b < 125) {
    int wave = tid >> 6, lane = tid & 63;
    int j = b * 4 + wave;
    float pa = 0.f;
    for (int k = lane; k < 1250; k += 64) pa += fabsf(lw[j * 1250 + k]);
    for (int o = 32; o > 0; o >>= 1) pa += __shfl_down(pa, o, 64);
    if (lane == 0) alpha[j] = pa / 1250.0f;
    if (lane < 20) {
      unsigned long long m = 0;
      int base = j * 1250 + lane * 64;
      int lim = 1250 - lane * 64; if (lim > 64) lim = 64;
      for (int bb = 0; bb < lim; ++bb)
        if (lw[base + bb] > 0.f) m |= (1ull << bb);
      lwp[j * 20 + lane] = m;
    }
  } else if (b < 130) {
    int idx = (b - 125) * 256 + tid;
    if (idx < 1250) {
      int oc = idx / 25, k = idx % 25;
      uint32_t m = 0;
      for (int ic = 0; ic < 20; ++ic)
        if (w2[(oc * 20 + ic) * 25 + k] > 0.f) m |= (1u << ic);
      wp2[idx] = m;
    }
  } else {
    int sb = b - 130;
    const float4* xv = (const float4*)x + (size_t)sb * 16 * 256;
    float ax = 0.f, ay = 0.f, az = 0.f, aw = 0.f;
    for (int nn = 0; nn < 16; ++nn) {
      float4 v = xv[nn * 256 + tid];
      ax += v.x; ay += v.y; az += v.z; aw += v.w;
    }
    float4 r; r.x = ax; r.y = ay; r.z = az; r.w = aw;
    ((float4*)(partial + (size_t)sb * 1024))[tid] = r;
  }
}

__global__ __launch_bounds__(256) void reduce_k(const float* __restrict__ partial,
                                                float* __restrict__ partial2) {
  int b = blockIdx.x, tid = threadIdx.x;
  int e = (b & 3) * 256 + tid;
  int p0 = (b >> 2) * 32;
  float s = 0.f;
#pragma unroll
  for (int p = 0; p < 32; ++p) s += partial[(size_t)(p0 + p) * 1024 + e];
  partial2[(size_t)(b >> 2) * 1024 + e] = s;
}

__global__ __launch_bounds__(256) void mean_k(const float* __restrict__ partial2,
                                              const float* __restrict__ w1,
                                              float* __restrict__ mean) {
  __shared__ float Tsh[1024];
  __shared__ double U8[25][8];
  __shared__ double U[25];
  int t = threadIdx.x;
  for (int e = t; e < 1024; e += 256) {
    double s = 0.0;
#pragma unroll
    for (int b = 0; b < 16; ++b) s += (double)partial2[b * 1024 + e];
    Tsh[e] = (float)s;
  }
  __syncthreads();
  if (t < 200) {
    int tap = t >> 3, part = t & 7;
    int ky = tap / 5, kx = tap % 5;
    double s = 0.0;
    for (int p = part * 98; p < part * 98 + 98; ++p) {
      int py = p / 28, px = p % 28;
      s += (double)Tsh[(py + ky) * 32 + px + kx];
    }
    U8[tap][part] = s;
  }
  __syncthreads();
  if (t < 25) {
    double s = 0.0;
    for (int i = 0; i < 8; ++i) s += U8[t][i];
    U[t] = s;
  }
  __syncthreads();
  if (t < 20) {
    double s = 0.0;
    for (int q = 0; q < 25; ++q) s += (double)w1[t * 25 + q] * U[q];
    mean[t] = (float)(s / (8192.0 * 784.0));
  }
}

__device__ inline uint32_t pack_f16_pair(float fv) {
  _Float16 h = (_Float16)fv;
  float rem = fv - (float)h;
  _Float16 l = (_Float16)(rem * 4096.0f);
  uint32_t hb = (uint32_t)__builtin_bit_cast(unsigned short, h);
  uint32_t lb = (uint32_t)__builtin_bit_cast(unsigned short, l);
  return (hb << 16) | lb;
}

// conv1 via MFMA (fp16 2-limb, single 4096-scaled acc chain).
// Block = 256 thr = 4 waves = 2 images; 2 waves per image (7 row-pairs each).
__global__ __launch_bounds__(256, 6) void conv1_mfma_k(const float* __restrict__ x,
                                                       const float* __restrict__ w1,
                                                       const float* __restrict__ mean,
                                                       uint32_t* __restrict__ b1p) {
  __shared__ uint32_t ximg[2][1032];
  int tid = threadIdx.x;
  int wave = tid >> 6, lane = tid & 63;
  int img = wave >> 1, half = wave & 1;
  int n = blockIdx.x * 2 + img;
  uint32_t* xs = ximg[img];

  // ---- stage image halves (2 waves cooperate) ----
  const float4* xin = (const float4*)(x + (size_t)n * 1024);
#pragma unroll
  for (int i = 0; i < 2; ++i) {
    int idx = (half * 2 + i) * 64 + lane;
    float4 v = xin[idx];
    float fv[4] = {v.x, v.y, v.z, v.w};
#pragma unroll
    for (int e = 0; e < 4; ++e)
      xs[4 * idx + e] = pack_f16_pair(fv[e]);
  }
  if (half == 0 && lane < 8) xs[1024 + lane] = 0;  // pad slots

  // ---- B fragments: Bh (hi), Bhs (hi*4096 exact), Bl (lo*4096) ----
  int bc = lane & 31;
  int khsel = lane >> 5;
  f16x8 Bh[2], Bhs[2], Bl[2];
  const int t1tab[8] = {8, 9, 18, 19, 20, 21, 22, 23};
  const _Float16 SC = (_Float16)4096.0f;
#pragma unroll
  for (int j = 0; j < 8; ++j) {
    int t0 = j + khsel * 10;
    float wv0 = (bc < 20) ? w1[bc * 25 + t0] : 0.f;
    uint32_t p0 = pack_f16_pair(wv0);
    _Float16 h0 = __builtin_bit_cast(_Float16, (unsigned short)(p0 >> 16));
    Bh[0][j] = h0;
    Bhs[0][j] = h0 * SC;
    Bl[0][j] = __builtin_bit_cast(_Float16, (unsigned short)(p0 & 0xffffu));
    float wv1 = 0.f;
    if (bc < 20) {
      if (khsel == 0) wv1 = w1[bc * 25 + t1tab[j]];
      else if (j == 4) wv1 = w1[bc * 25 + 24];
    }
    uint32_t p1 = pack_f16_pair(wv1);
    _Float16 h1 = __builtin_bit_cast(_Float16, (unsigned short)(p1 >> 16));
    Bh[1][j] = h1;
    Bhs[1][j] = h1 * SC;
    Bl[1][j] = __builtin_bit_cast(_Float16, (unsigned short)(p1 & 0xffffu));
  }
  float mv = (bc < 20) ? mean[bc] * 4096.0f : 3.0e38f;

  int m = lane & 31;
  int d0 = m + khsel * 64;
  int d1 = m + khsel * 4;

  __syncthreads();

  int pp0 = half * 7;
  for (int pp = pp0; pp < pp0 + 7; ++pp) {
    unsigned long long bacc[16];
#pragma unroll
    for (int r = 0; r < 16; ++r) bacc[r] = 0ull;
#pragma unroll
    for (int py2 = 0; py2 < 2; ++py2) {
      int pybase = (2 * pp + py2) * 32;
      const uint32_t* b0 = xs + pybase + d0;
      const uint32_t* b1 = xs + pybase + d1;
      uint32_t raw[16];
      raw[0] = b0[0];   raw[1] = b0[1];   raw[2] = b0[2];   raw[3] = b0[3];
      raw[4] = b0[4];   raw[5] = b0[32];  raw[6] = b0[33];  raw[7] = b0[34];
      raw[8] = b1[35];  raw[9] = b1[36];  raw[10] = b1[99]; raw[11] = b1[100];
      raw[12] = b1[128]; raw[13] = b1[129]; raw[14] = b1[130]; raw[15] = b1[131];
      f16x8 Ah[2], Al[2];
#pragma unroll
      for (int kh = 0; kh < 2; ++kh) {
        uint32_t hw[4], lw2[4];
#pragma unroll
        for (int jj = 0; jj < 4; ++jj) {
          uint32_t v0 = raw[kh * 8 + 2 * jj], v1 = raw[kh * 8 + 2 * jj + 1];
          hw[jj] = __builtin_amdgcn_perm(v1, v0, 0x07060302u);
          lw2[jj] = __builtin_amdgcn_perm(v1, v0, 0x05040100u);
        }
        struct U4 { uint32_t a, b, c, d; };
        U4 hv4 = {hw[0], hw[1], hw[2], hw[3]};
        U4 lv4 = {lw2[0], lw2[1], lw2[2], lw2[3]};
        Ah[kh] = __builtin_bit_cast(f16x8, hv4);
        Al[kh] = __builtin_bit_cast(f16x8, lv4);
      }
      f32x16 acc;
#pragma unroll
      for (int i = 0; i < 16; ++i) acc[i] = 0.f;
      acc = __builtin_amdgcn_mfma_f32_32x32x16_f16(Ah[0], Bhs[0], acc, 0, 0, 0);
      acc = __builtin_amdgcn_mfma_f32_32x32x16_f16(Ah[1], Bhs[1], acc, 0, 0, 0);
      acc = __builtin_amdgcn_mfma_f32_32x32x16_f16(Ah[0], Bl[0], acc, 0, 0, 0);
      acc = __builtin_amdgcn_mfma_f32_32x32x16_f16(Ah[1], Bl[1], acc, 0, 0, 0);
      acc = __builtin_amdgcn_mfma_f32_32x32x16_f16(Al[0], Bh[0], acc, 0, 0, 0);
      acc = __builtin_amdgcn_mfma_f32_32x32x16_f16(Al[1], Bh[1], acc, 0, 0, 0);
      // C/D: channel = lane&31, px = (r&3) + 8*(r>>2) + 4*(lane>>5)
#pragma unroll
      for (int r = 0; r < 16; ++r)
        bacc[r] |= __ballot(acc[r] > mv);
    }
    uint32_t pm = 0;
#pragma unroll
    for (int pc = 0; pc < 14; ++pc) {
      int px0 = 2 * pc;
      int r0 = (px0 & 3) + 4 * (px0 >> 3);
      int h0 = (px0 >> 2) & 1;
      unsigned long long mm = bacc[r0] | bacc[r0 + 1];
      uint32_t val = (uint32_t)(mm >> (32 * h0));
      if (lane == pc) pm = val;
    }
    if (lane < 14) b1p[(size_t)n * 196 + pp * 14 + lane] = pm;
  }
}

// Fused conv2+pool/sign+linear+fc. Round-10..13 version verbatim.
__global__ __launch_bounds__(512) void conv2lin_k(const uint32_t* __restrict__ b1p,
                                                  const uint32_t* __restrict__ wp2,
                                                  const unsigned long long* __restrict__ lwp,
                                                  const float* __restrict__ alpha,
                                                  const float* __restrict__ fcw,
                                                  const float* __restrict__ fcb,
                                                  float* __restrict__ out) {
  __shared__ uint32_t wsh[1250];
  __shared__ uint32_t bm[8][196];
  __shared__ int sumpc[8][100];
  __shared__ char uni[8][2048];
  int tid = threadIdx.x;
  int wave = tid >> 6, lane = tid & 63;
  int n = blockIdx.x * 8 + wave;
  signed char* s2w = (signed char*)uni[wave];
  float* hshw = (float*)uni[wave];

  for (int i = tid; i < 1250; i += 512) wsh[i] = wp2[i];
#pragma unroll
  for (int rd = 0; rd < 4; ++rd) {
    int idx = rd * 64 + lane;
    if (idx < 196) bm[wave][idx] = b1p[(size_t)n * 196 + idx];
  }
  __syncthreads();

#pragma unroll
  for (int rd = 0; rd < 2; ++rd) {
    int pp = rd * 64 + lane;
    if (pp < 100) {
      int Y = pp / 10, X = pp % 10, s = 0;
#pragma unroll
      for (int ky = 0; ky < 5; ++ky)
#pragma unroll
        for (int kx = 0; kx < 5; ++kx)
          s += __popc(bm[wave][(Y + ky) * 14 + X + kx]);
      sumpc[wave][pp] = s;
    }
  }

#pragma unroll
  for (int rd = 0; rd < 4; ++rd) {
    int unit = rd * 64 + lane;
    if (unit < 250) {
      int oc = unit / 5, r = unit % 5;
      uint32_t w[25];
#pragma unroll
      for (int i = 0; i < 25; ++i) w[i] = wsh[oc * 25 + i];
      for (int pc = 0; pc < 5; ++pc) {
        uint32_t pa[6][6];
#pragma unroll
        for (int rr = 0; rr < 6; ++rr)
#pragma unroll
          for (int cc = 0; cc < 6; ++cc)
            pa[rr][cc] = bm[wave][(2 * r + rr) * 14 + 2 * pc + cc];
        int best = -1000000;
#pragma unroll
        for (int dy = 0; dy < 2; ++dy)
#pragma unroll
          for (int dx = 0; dx < 2; ++dx) {
            int a = 0;
#pragma unroll
            for (int ky = 0; ky < 5; ++ky)
#pragma unroll
              for (int kx = 0; kx < 5; ++kx)
                a += __popc(w[ky * 5 + kx] & pa[dy + ky][dx + kx]);
            a = 2 * a - sumpc[wave][(2 * r + dy) * 10 + 2 * pc + dx];
            if (a > best) best = a;
          }
        s2w[5 * unit + pc] = (signed char)((best > 0) - (best < 0));
      }
    }
  }
  if (lane < 30) s2w[1250 + lane] = 0;

  unsigned long long Pm[20], Nm[20];
  int cp = 0, cn = 0;
#pragma unroll
  for (int k = 0; k < 20; ++k) {
    signed char v = s2w[k * 64 + lane];
    unsigned long long P = __ballot(v > 0);
    unsigned long long N = __ballot(v < 0);
    Pm[k] = P; Nm[k] = N;
    cp += __popcll(P); cn += __popcll(N);
  }

#pragma unroll
  for (int rd = 0; rd < 8; ++rd) {
    int j = rd * 64 + lane;
    float y = 0.f;
    if (j < 500) {
      const ulonglong2* W2 = (const ulonglong2*)(lwp + (size_t)j * 20);
      int a = 0, b = 0;
#pragma unroll
      for (int i = 0; i < 10; ++i) {
        ulonglong2 w2v = W2[i];
        a += __popcll(w2v.x & Pm[2 * i]) + __popcll(w2v.y & Pm[2 * i + 1]);
        b += __popcll(w2v.x & Nm[2 * i]) + __popcll(w2v.y & Nm[2 * i + 1]);
      }
      int dot = 2 * (a - b) - cp + cn;
      y = alpha[j] * (float)dot;
      y = fminf(1.0f, fmaxf(-1.0f, y));
    }
    hshw[rd * 64 + lane] = y;
  }

  float hv[8];
#pragma unroll
  for (int k = 0; k < 8; ++k) hv[k] = hshw[k * 64 + lane];
#pragma unroll
  for (int o = 0; o < 10; ++o) {
    float pa = 0.f;
#pragma unroll
    for (int k = 0; k < 8; ++k) {
      int j = k * 64 + lane;
      if (j < 500) pa += hv[k] * fcw[o * 500 + j];
    }
    for (int off = 32; off > 0; off >>= 1) pa += __shfl_down(pa, off, 64);
    if (lane == 0) out[(size_t)n * 10 + o] = pa + fcb[o];
  }
}

extern "C" void kernel_launch(void* const* d_in, const int* in_sizes, int n_in,
                              void* d_out, int out_size, void* d_ws, size_t ws_size,
                              hipStream_t stream) {
  const float* x   = (const float*)d_in[0];
  const float* w1  = (const float*)d_in[1];
  const float* w2  = (const float*)d_in[2];
  const float* lw  = (const float*)d_in[3];
  const float* fcw = (const float*)d_in[4];
  const float* fcb = (const float*)d_in[5];
  float* out = (float*)d_out;
  char* ws = (char*)d_ws;

  float*    mean  = (float*)(ws + 0);
  uint32_t* wp2   = (uint32_t*)(ws + 128);
  float*    alpha = (float*)(ws + 5632);
  unsigned long long* lwp = (unsigned long long*)(ws + 7680);
  float*    partial = (float*)(ws + 87808);
  uint32_t* b1p   = (uint32_t*)(ws + 2184960);
  float*    partial2 = (float*)(ws + 8607488);

  prepsum_k<<<642, 256, 0, stream>>>(lw, w2, x, lwp, alpha, wp2, partial);
  reduce_k<<<64, 256, 0, stream>>>(partial, partial2);
  mean_k<<<1, 256, 0, stream>>>(partial2, w1, mean);
  conv1_mfma_k<<<4096, 256, 0, stream>>>(x, w1, mean, b1p);
  conv2lin_k<<<1024, 512, 0, stream>>>(b1p, wp2, lwp, alpha, fcw, fcb, out);
}